// Round 10
// baseline (167.941 us; speedup 1.0000x reference)
//
#include <hip/hip_runtime.h>
#include <hip/hip_fp16.h>

#define NG 32
#define BATCH 4096

typedef float fvec4 __attribute__((ext_vector_type(4)));   // native vec for nontemporal builtins

// level1: [33][33][32][16][32] f32 -> T1[(x*32+z)*1089 + a*33+b'][o] fp16
// level0: [33][33][64][16]     f32 -> T0[(p*1089 + a*33+b')*64 + h]  f32
static constexpr size_t T1H_BYTES = 17842176ull * 2;
static constexpr size_t T0F_BYTES = 1115136ull * 4;

__device__ __forceinline__ void interp1(float v, const float* sb, const float* sil,
                                        int& i, float& d) {
    float e = expf(-fabsf(v));
    float s = (v > 0.f) ? (1.f - 0.5f * e) : (0.5f * e);
    s *= (float)NG;
    int ii = (int)s;                       // trunc (s >= 0)
    ii = ii < 0 ? 0 : (ii > NG - 1 ? NG - 1 : ii);
    d = (v - sb[ii]) * sil[ii];
    i = ii;
}

// ---------------------------------------------------------------------------
// Kernel 1: transpose tables (one block per cell a*33+b').
// T1 path: register-blocked transpose, NO LDS. Each thread: 8 coalesced
// fvec4 nontemporal loads (8 o-rows x 4 xz), pack to fp16, 4 uint4 stores
// (4 T1 rows, consecutive 16B pieces of 64B rows -> merged in L2).
// T0 path: small LDS transpose.
// ---------------------------------------------------------------------------
__global__ __launch_bounds__(256) void k_transpose(
    const float* __restrict__ L1, const float* __restrict__ L0,
    __half* __restrict__ T1, float* __restrict__ T0)
{
    __shared__ float fbuf[64 * 17];    // [h][p] pad
    const int cell = blockIdx.x;
    const int tid = threadIdx.x;
    const int w = tid >> 6, lane = tid & 63;

    // stage T0 source (coalesced, nontemporal)
    const float* L0s = L0 + (size_t)cell * 1024;
#pragma unroll
    for (int k = 0; k < 4; ++k) {
        int t = tid + k * 256;
        int h = t >> 4, p = t & 15;
        fbuf[h * 17 + p] = __builtin_nontemporal_load(&L0s[t]);
    }

    // T1 register transpose: lane -> xz0 consecutive (coalesced loads)
    const fvec4* L1v = reinterpret_cast<const fvec4*>(L1 + (size_t)cell * 16384);
    const int xz0 = (w & 1) * 256 + lane * 4;
    const int o0b = (w >> 1) * 8;
#pragma unroll
    for (int q = 0; q < 2; ++q) {
        const int o0 = o0b + 16 * q;
        float fa[8][4];
#pragma unroll
        for (int j = 0; j < 8; ++j) {
            fvec4 f = __builtin_nontemporal_load(&L1v[(o0 + j) * 128 + (xz0 >> 2)]);
            fa[j][0] = f.x; fa[j][1] = f.y; fa[j][2] = f.z; fa[j][3] = f.w;
        }
#pragma unroll
        for (int k = 0; k < 4; ++k) {
            union { uint4 u; __half2 h[4]; } row;
            row.h[0] = __float22half2_rn(make_float2(fa[0][k], fa[1][k]));
            row.h[1] = __float22half2_rn(make_float2(fa[2][k], fa[3][k]));
            row.h[2] = __float22half2_rn(make_float2(fa[4][k], fa[5][k]));
            row.h[3] = __float22half2_rn(make_float2(fa[6][k], fa[7][k]));
            *reinterpret_cast<uint4*>(&T1[((size_t)(xz0 + k) * 1089 + cell) * 32 + o0]) = row.u;
        }
    }

    __syncthreads();
    // T0 store (coalesced over h)
#pragma unroll
    for (int k = 0; k < 4; ++k) {
        int t = tid + k * 256;
        int p = t >> 6, h = t & 63;
        T0[((size_t)p * 1089 + cell) * 64 + h] = fbuf[h * 17 + p];
    }
}

// ---------------------------------------------------------------------------
// Kernel 2: fused prep + main gather-accumulate. Block = 4 batch elems.
// Main-loop lane layout: lane = zs*8 + jc*4 + oh
//   -> each load instr: 8 lanes cover 128B contiguous (2 j-corners x 32 o fp16)
// launch_bounds (256,8): ~2x waves vs R5 to hide L2/LLC gather latency.
// ---------------------------------------------------------------------------
__device__ __forceinline__ void accumh2(__half2 acc[4], uint4 u, __half2 c) {
    union { unsigned u32; __half2 h2; } cv;
    cv.u32 = u.x; acc[0] = __hfma2(c, cv.h2, acc[0]);
    cv.u32 = u.y; acc[1] = __hfma2(c, cv.h2, acc[1]);
    cv.u32 = u.z; acc[2] = __hfma2(c, cv.h2, acc[2]);
    cv.u32 = u.w; acc[3] = __hfma2(c, cv.h2, acc[3]);
}

__global__ __launch_bounds__(256, 8) void k_fused(
    const float* __restrict__ X, const float* __restrict__ T0,
    const __half* __restrict__ T1,
    const float* __restrict__ borders, const float* __restrict__ invlen,
    float* __restrict__ out)
{
    __shared__ float sb[33], sil[32];
    __shared__ int   scell[16][4];
    __shared__ float ssw[4][16][4];
    __shared__ float sz0[4][64];
    __shared__ int   si1[16][4];
    __shared__ float sX0[16][4], sX1[16][4];
    __shared__ int   sj1[32][4];
    __shared__ float sZ[2][32][4];

    const int tid = threadIdx.x;
    const int b0 = blockIdx.x * 4;

    if (tid < 33) sb[tid] = borders[tid];
    if (tid >= 64 && tid < 96) sil[tid - 64] = invlen[tid - 64];
    __syncthreads();

    // phase 0: first-level interp (16 p x 4 b)
    if (tid < 64) {
        const int p = tid & 15, bl = tid >> 4;
        const int b = b0 + bl;
        float x1 = X[(2 * p) * BATCH + b];
        float x2 = X[(2 * p + 1) * BATCH + b];
        int i1, i2; float d1, d2;
        interp1(x1, sb, sil, i1, d1);
        interp1(x2, sb, sil, i2, d2);
        float w00 = (1.f - d1) * (1.f - d2);
        float w01 = (1.f - d1) * d2;
        float w10 = d1 * (1.f - d2);
        float w11 = d1 * d2;
        scell[p][bl] = i1 * 33 + i2;
        ssw[0][p][bl] = w00; ssw[1][p][bl] = w01; ssw[2][p][bl] = w10; ssw[3][p][bl] = w11;
        si1[p][bl] = i1;
        sX0[p][bl] = w00;   // pairs corner i1
        sX1[p][bl] = w10;   // pairs corner i1+1
    }
    __syncthreads();

    // phase 1: z0[h] (64 h-lanes x 4 b, coalesced 256B loads from T0)
    {
        const int h = tid & 63, bl = tid >> 6;
        float acc = 0.f;
#pragma unroll 4
        for (int p = 0; p < 16; ++p) {
            int cell = scell[p][bl];
            unsigned basep = ((unsigned)p * 1089u + (unsigned)cell) * 64u + (unsigned)h;
            float t00 = T0[basep];
            float t01 = T0[basep + 64];
            float t10 = T0[basep + 33 * 64];
            float t11 = T0[basep + 34 * 64];
            acc += ssw[0][p][bl] * t00 + ssw[1][p][bl] * t01 + ssw[2][p][bl] * t10 + ssw[3][p][bl] * t11;
        }
        sz0[bl][h] = acc;
    }
    __syncthreads();

    // phase 2: second-level interp (32 z x 4 b)
    if (tid < 128) {
        const int z = tid & 31, bl = tid >> 5;
        float z1 = sz0[bl][2 * z];
        float z2 = sz0[bl][2 * z + 1];
        int j1, j2u; float dz1, dz2;
        interp1(z1, sb, sil, j1, dz1);
        interp1(z2, sb, sil, j2u, dz2);
        (void)j2u;
        sj1[z][bl] = j1;
        sZ[0][z][bl] = (1.f - dz1) * (1.f - dz2);  // corner j1
        sZ[1][z][bl] = dz1 * (1.f - dz2);          // corner j1+1
    }
    __syncthreads();

    // phase 3: main gather loop
    const int lane = tid & 63, bl = tid >> 6;
    const int b = b0 + bl;
    const int oh = lane & 3;
    const int jc = (lane >> 2) & 1;
    const int zs = lane >> 3;
    const unsigned loff = (unsigned)(jc * 32 + oh * 8);

    __half2 acc2[4];
#pragma unroll
    for (int k = 0; k < 4; ++k) acc2[k] = __half2half2(__float2half(0.f));

#pragma unroll 2
    for (int x = 0; x < 16; ++x) {
        const int cb = si1[x][bl] * 33;
        const float X0 = sX0[x][bl], X1 = sX1[x][bl];
        const unsigned xzb = (unsigned)(x * 32 + zs * 4) * 1089u;
#pragma unroll
        for (int zi = 0; zi < 4; ++zi) {
            const int z = zs * 4 + zi;
            const unsigned cell = (unsigned)(cb + sj1[z][bl]);
            const float Zc = sZ[jc][z][bl];
            const unsigned base = (xzb + (unsigned)zi * 1089u + cell) * 32u + loff;
            uint4 u0 = *reinterpret_cast<const uint4*>(T1 + base);            // (i1,   j1+jc)
            uint4 u1 = *reinterpret_cast<const uint4*>(T1 + base + 33 * 32);  // (i1+1, j1+jc)
            const float c0 = X0 * Zc, c1 = X1 * Zc;
            accumh2(acc2, u0, __float2half2_rn(c0));
            accumh2(acc2, u1, __float2half2_rn(c1));
        }
    }

    // unpack to fp32, butterfly-reduce over jc (mask 4) and zs (8,16,32)
    float accf[8];
#pragma unroll
    for (int k = 0; k < 4; ++k) {
        float2 f = __half22float2(acc2[k]);
        accf[2 * k] = f.x; accf[2 * k + 1] = f.y;
    }
#pragma unroll
    for (int m = 4; m <= 32; m <<= 1) {
#pragma unroll
        for (int k = 0; k < 8; ++k) accf[k] += __shfl_xor(accf[k], m, 64);
    }
    if (lane < 4) {
#pragma unroll
        for (int k = 0; k < 8; ++k)
            __builtin_nontemporal_store(accf[k], &out[(oh * 8 + k) * BATCH + b]);
    }
}

extern "C" void kernel_launch(void* const* d_in, const int* in_sizes, int n_in,
                              void* d_out, int out_size, void* d_ws, size_t ws_size,
                              hipStream_t stream) {
    const float* X       = (const float*)d_in[0];
    const float* L0      = (const float*)d_in[1];
    const float* L1      = (const float*)d_in[2];
    const float* borders = (const float*)d_in[3];
    const float* invlen  = (const float*)d_in[4];
    float* out = (float*)d_out;

    char* ws = (char*)d_ws;
    __half* T1h = (__half*)ws;
    float*  T0f = (float*)(ws + T1H_BYTES);

    hipLaunchKernelGGL(k_transpose, dim3(1089), dim3(256), 0, stream, L1, L0, T1h, T0f);
    hipLaunchKernelGGL(k_fused, dim3(BATCH / 4), dim3(256), 0, stream,
                       X, T0f, T1h, borders, invlen, out);
}

// Round 11
// 148.782 us; speedup vs baseline: 1.1288x; 1.1288x over previous
//
#include <hip/hip_runtime.h>
#include <hip/hip_fp16.h>

#define NG 32
#define BATCH 4096

// level1: [33][33][32][16][32] f32 -> T1[(x*32+z)*1089 + a*33+b'][o] fp16
// level0: [33][33][64][16]     f32 -> T0[(p*1089 + a*33+b')*64 + h]  f32
static constexpr size_t T1H_BYTES = 17842176ull * 2;
static constexpr size_t T0F_BYTES = 1115136ull * 4;

__device__ __forceinline__ void interp1(float v, const float* sb, const float* sil,
                                        int& i, float& d) {
    float e = expf(-fabsf(v));
    float s = (v > 0.f) ? (1.f - 0.5f * e) : (0.5f * e);
    s *= (float)NG;
    int ii = (int)s;                       // trunc (s >= 0)
    ii = ii < 0 ? 0 : (ii > NG - 1 ? NG - 1 : ii);
    d = (v - sb[ii]) * sil[ii];
    i = ii;
}

// ---------------------------------------------------------------------------
// Kernel 1: transpose tables (one block per cell a*33+b').
// R5 version (measured): LDS-staged, 4 lanes cover one 64B T1 row segment.
// ---------------------------------------------------------------------------
__global__ __launch_bounds__(256) void k_transpose(
    const float* __restrict__ L1, const float* __restrict__ L0,
    __half* __restrict__ T1, float* __restrict__ T0)
{
    __shared__ __half hbuf[32 * 516];   // [o][xz] pad: 8B-aligned rows
    __shared__ float  fbuf[64 * 17];    // [h][p] pad
    const int cell = blockIdx.x;
    const int tid = threadIdx.x;

    const float4* L1v = reinterpret_cast<const float4*>(L1 + (size_t)cell * 16384);
#pragma unroll
    for (int k = 0; k < 16; ++k) {
        int v = tid + k * 256;
        int idx = v * 4;
        int o = idx >> 9, r = idx & 511;
        float4 f = L1v[v];
        *reinterpret_cast<__half2*>(&hbuf[o * 516 + r])     = __float22half2_rn(make_float2(f.x, f.y));
        *reinterpret_cast<__half2*>(&hbuf[o * 516 + r + 2]) = __float22half2_rn(make_float2(f.z, f.w));
    }
    const float* L0s = L0 + (size_t)cell * 1024;
#pragma unroll
    for (int k = 0; k < 4; ++k) {
        int t = tid + k * 256;
        int h = t >> 4, p = t & 15;
        fbuf[h * 17 + p] = L0s[t];
    }
    __syncthreads();

#pragma unroll
    for (int k = 0; k < 8; ++k) {
        int t = tid + k * 256;
        int xz = t >> 2, o0 = (t & 3) * 8;
        __half tmp[8];
#pragma unroll
        for (int j = 0; j < 8; ++j) tmp[j] = hbuf[(o0 + j) * 516 + xz];
        *reinterpret_cast<uint4*>(&T1[((size_t)xz * 1089 + cell) * 32 + o0]) =
            *reinterpret_cast<const uint4*>(tmp);
    }
#pragma unroll
    for (int k = 0; k < 4; ++k) {
        int t = tid + k * 256;
        int p = t >> 6, h = t & 63;
        T0[((size_t)p * 1089 + cell) * 64 + h] = fbuf[h * 17 + p];
    }
}

// ---------------------------------------------------------------------------
// Kernel 2: fused prep + main gather-accumulate. Block = 4 batch elems.
// Identical to R5 except __launch_bounds__(256, 8): 8 waves/SIMD (VGPR cap
// 64) to hide L2/LLC gather latency — the single isolated variable vs R5.
// ---------------------------------------------------------------------------
__device__ __forceinline__ void accumh2(__half2 acc[4], uint4 u, __half2 c) {
    union { unsigned u32; __half2 h2; } cv;
    cv.u32 = u.x; acc[0] = __hfma2(c, cv.h2, acc[0]);
    cv.u32 = u.y; acc[1] = __hfma2(c, cv.h2, acc[1]);
    cv.u32 = u.z; acc[2] = __hfma2(c, cv.h2, acc[2]);
    cv.u32 = u.w; acc[3] = __hfma2(c, cv.h2, acc[3]);
}

__global__ __launch_bounds__(256, 8) void k_fused(
    const float* __restrict__ X, const float* __restrict__ T0,
    const __half* __restrict__ T1,
    const float* __restrict__ borders, const float* __restrict__ invlen,
    float* __restrict__ out)
{
    __shared__ float sb[33], sil[32];
    __shared__ int   scell[16][4];
    __shared__ float ssw[4][16][4];
    __shared__ float sz0[4][64];
    __shared__ int   si1[16][4];
    __shared__ float sX0[16][4], sX1[16][4];
    __shared__ int   sj1[32][4];
    __shared__ float sZ[2][32][4];

    const int tid = threadIdx.x;
    const int b0 = blockIdx.x * 4;

    if (tid < 33) sb[tid] = borders[tid];
    if (tid >= 64 && tid < 96) sil[tid - 64] = invlen[tid - 64];
    __syncthreads();

    // phase 0: first-level interp (16 p x 4 b)
    if (tid < 64) {
        const int p = tid & 15, bl = tid >> 4;
        const int b = b0 + bl;
        float x1 = X[(2 * p) * BATCH + b];
        float x2 = X[(2 * p + 1) * BATCH + b];
        int i1, i2; float d1, d2;
        interp1(x1, sb, sil, i1, d1);
        interp1(x2, sb, sil, i2, d2);
        float w00 = (1.f - d1) * (1.f - d2);
        float w01 = (1.f - d1) * d2;
        float w10 = d1 * (1.f - d2);
        float w11 = d1 * d2;
        scell[p][bl] = i1 * 33 + i2;
        ssw[0][p][bl] = w00; ssw[1][p][bl] = w01; ssw[2][p][bl] = w10; ssw[3][p][bl] = w11;
        si1[p][bl] = i1;
        sX0[p][bl] = w00;   // pairs corner i1
        sX1[p][bl] = w10;   // pairs corner i1+1
    }
    __syncthreads();

    // phase 1: z0[h] (64 h-lanes x 4 b, coalesced 256B loads from T0)
    {
        const int h = tid & 63, bl = tid >> 6;
        float acc = 0.f;
#pragma unroll 4
        for (int p = 0; p < 16; ++p) {
            int cell = scell[p][bl];
            unsigned basep = ((unsigned)p * 1089u + (unsigned)cell) * 64u + (unsigned)h;
            float t00 = T0[basep];
            float t01 = T0[basep + 64];
            float t10 = T0[basep + 33 * 64];
            float t11 = T0[basep + 34 * 64];
            acc += ssw[0][p][bl] * t00 + ssw[1][p][bl] * t01 + ssw[2][p][bl] * t10 + ssw[3][p][bl] * t11;
        }
        sz0[bl][h] = acc;
    }
    __syncthreads();

    // phase 2: second-level interp (32 z x 4 b)
    if (tid < 128) {
        const int z = tid & 31, bl = tid >> 5;
        float z1 = sz0[bl][2 * z];
        float z2 = sz0[bl][2 * z + 1];
        int j1, j2u; float dz1, dz2;
        interp1(z1, sb, sil, j1, dz1);
        interp1(z2, sb, sil, j2u, dz2);
        (void)j2u;
        sj1[z][bl] = j1;
        sZ[0][z][bl] = (1.f - dz1) * (1.f - dz2);  // corner j1
        sZ[1][z][bl] = dz1 * (1.f - dz2);          // corner j1+1
    }
    __syncthreads();

    // phase 3: main gather loop
    const int lane = tid & 63, bl = tid >> 6;
    const int b = b0 + bl;
    const int oh = lane & 3;
    const int jc = (lane >> 2) & 1;
    const int zs = lane >> 3;
    const unsigned loff = (unsigned)(jc * 32 + oh * 8);

    __half2 acc2[4];
#pragma unroll
    for (int k = 0; k < 4; ++k) acc2[k] = __half2half2(__float2half(0.f));

#pragma unroll 2
    for (int x = 0; x < 16; ++x) {
        const int cb = si1[x][bl] * 33;
        const float X0 = sX0[x][bl], X1 = sX1[x][bl];
        const unsigned xzb = (unsigned)(x * 32 + zs * 4) * 1089u;
#pragma unroll
        for (int zi = 0; zi < 4; ++zi) {
            const int z = zs * 4 + zi;
            const unsigned cell = (unsigned)(cb + sj1[z][bl]);
            const float Zc = sZ[jc][z][bl];
            const unsigned base = (xzb + (unsigned)zi * 1089u + cell) * 32u + loff;
            uint4 u0 = *reinterpret_cast<const uint4*>(T1 + base);            // (i1,   j1+jc)
            uint4 u1 = *reinterpret_cast<const uint4*>(T1 + base + 33 * 32);  // (i1+1, j1+jc)
            const float c0 = X0 * Zc, c1 = X1 * Zc;
            accumh2(acc2, u0, __float2half2_rn(c0));
            accumh2(acc2, u1, __float2half2_rn(c1));
        }
    }

    // unpack to fp32, butterfly-reduce over jc (mask 4) and zs (8,16,32)
    float accf[8];
#pragma unroll
    for (int k = 0; k < 4; ++k) {
        float2 f = __half22float2(acc2[k]);
        accf[2 * k] = f.x; accf[2 * k + 1] = f.y;
    }
#pragma unroll
    for (int m = 4; m <= 32; m <<= 1) {
#pragma unroll
        for (int k = 0; k < 8; ++k) accf[k] += __shfl_xor(accf[k], m, 64);
    }
    if (lane < 4) {
#pragma unroll
        for (int k = 0; k < 8; ++k) out[(oh * 8 + k) * BATCH + b] = accf[k];
    }
}

extern "C" void kernel_launch(void* const* d_in, const int* in_sizes, int n_in,
                              void* d_out, int out_size, void* d_ws, size_t ws_size,
                              hipStream_t stream) {
    const float* X       = (const float*)d_in[0];
    const float* L0      = (const float*)d_in[1];
    const float* L1      = (const float*)d_in[2];
    const float* borders = (const float*)d_in[3];
    const float* invlen  = (const float*)d_in[4];
    float* out = (float*)d_out;

    char* ws = (char*)d_ws;
    __half* T1h = (__half*)ws;
    float*  T0f = (float*)(ws + T1H_BYTES);

    hipLaunchKernelGGL(k_transpose, dim3(1089), dim3(256), 0, stream, L1, L0, T1h, T0f);
    hipLaunchKernelGGL(k_fused, dim3(BATCH / 4), dim3(256), 0, stream,
                       X, T0f, T1h, borders, invlen, out);
}